// Round 14
// baseline (74.841 us; speedup 1.0000x reference)
//
#include <hip/hip_runtime.h>
#include <hip/hip_bf16.h>
#include <math.h>

#define B_    2
#define T_    1024
#define DIM_  1024
#define H_    16
#define D_    64
#define M_    (B_ * T_)      // 2048 rows
#define NQKV_ 3072
#define NTOT_ 4096
#define NC_   16             // chunks of 64 along T

typedef __attribute__((ext_vector_type(8))) short short8v;   // 8 bf16
typedef __attribute__((ext_vector_type(4))) float floatx4;

__device__ __forceinline__ float elu1(float x) {
    return x > 0.f ? x + 1.f : expf(x);
}
__device__ __forceinline__ unsigned short f2bf(float f) {
    unsigned int u = __float_as_uint(f);
    return (unsigned short)((u + 0x7FFFu + ((u >> 16) & 1u)) >> 16);   // RNE
}
__device__ __forceinline__ float bf2f(unsigned short s) {
    return __uint_as_float((unsigned int)s << 16);
}
// XOR-swizzled byte offset within a [rows][64]bf16 LDS tile (128B rows)
__device__ __forceinline__ int swzb(int row, int byte) {
    return row * 128 + (byte ^ ((row & 7) << 4));
}
// 4-slot swizzle for [rows][32]bf16 tiles (64B rows): max 2-way aliasing
__device__ __forceinline__ int swz4(int r) {
    return (r & 3) ^ ((r >> 2) & 3);
}
__device__ __forceinline__ void glds16(const unsigned short* g, short* l) {
    __builtin_amdgcn_global_load_lds(
        (const __attribute__((address_space(1))) unsigned int*)g,
        (__attribute__((address_space(3))) unsigned int*)l, 16, 0, 0);
}

// ---------------------------------------------------------------------------
// prep: fused cast_x + 3x weight transpose+cast.  Flat grid, role by blockIdx.
// ---------------------------------------------------------------------------
__device__ __forceinline__ void transw_body(
    const float* __restrict__ src, unsigned short* __restrict__ dst, int srcN,
    int n0, int k0, float (*t)[33], int tid) {
    const int r  = tid >> 3;
    const int c4 = (tid & 7) * 4;
    float4 v = *(const float4*)&src[(size_t)(k0 + r) * srcN + n0 + c4];
    t[c4 + 0][r] = v.x; t[c4 + 1][r] = v.y; t[c4 + 2][r] = v.z; t[c4 + 3][r] = v.w;
    __syncthreads();
    unsigned short o[4];
    o[0] = f2bf(t[tid >> 3][(tid & 7) * 4 + 0]);
    o[1] = f2bf(t[tid >> 3][(tid & 7) * 4 + 1]);
    o[2] = f2bf(t[tid >> 3][(tid & 7) * 4 + 2]);
    o[3] = f2bf(t[tid >> 3][(tid & 7) * 4 + 3]);
    *(unsigned long long*)&dst[(size_t)(n0 + (tid >> 3)) * 1024 + k0 + (tid & 7) * 4] =
        *(unsigned long long*)o;
}

__global__ __launch_bounds__(256) void prep(
    const float* __restrict__ x, const float* __restrict__ wqkv,
    const float* __restrict__ wgate, const float* __restrict__ wout,
    unsigned short* __restrict__ xb, unsigned short* __restrict__ wT,
    unsigned short* __restrict__ woutT) {
    __shared__ float t[32][33];
    const int blk = blockIdx.x;
    const int tid = threadIdx.x;
    if (blk < 1024) {
        int i = blk * 256 + tid;
        float4 v0 = ((const float4*)x)[i * 2];
        float4 v1 = ((const float4*)x)[i * 2 + 1];
        short8v o;
        o[0]=f2bf(v0.x); o[1]=f2bf(v0.y); o[2]=f2bf(v0.z); o[3]=f2bf(v0.w);
        o[4]=f2bf(v1.x); o[5]=f2bf(v1.y); o[6]=f2bf(v1.z); o[7]=f2bf(v1.w);
        *(short8v*)&xb[(size_t)i * 8] = o;
    } else if (blk < 4096) {
        int l = blk - 1024;
        transw_body(wqkv, wT, 3072, (l % 96) * 32, (l / 96) * 32, t, tid);
    } else if (blk < 5120) {
        int l = blk - 4096;
        transw_body(wgate, wT + (size_t)3072 * 1024, 1024, (l % 32) * 32, (l / 32) * 32, t, tid);
    } else {
        int l = blk - 5120;
        transw_body(wout, woutT, 1024, (l % 32) * 32, (l / 32) * 32, t, tid);
    }
}

// ---------------------------------------------------------------------------
// Kernel A: input GEMM 128x128, BK=32, 512 threads / 8 waves, dbuf LDS 32KB,
// __launch_bounds__(512,6) to cap VGPR (target 3 blocks/CU = 24 waves),
// counted vmcnt(2) + raw barriers, setprio around MFMA.
// Wave w owns rows [wr*32,+32) x cols [wc*64,+64), wr=w>>1, wc=w&1.
// ---------------------------------------------------------------------------
__global__ __launch_bounds__(512, 6) void gemm_in_mfma(
    const unsigned short* __restrict__ xb, const unsigned short* __restrict__ wT,
    unsigned short* __restrict__ qb, unsigned short* __restrict__ kb,
    unsigned short* __restrict__ vb, unsigned short* __restrict__ gtb) {
    __shared__ short As[2][128 * 32];      // 2 x 8 KB
    __shared__ short Bs[2][128 * 32];      // 2 x 8 KB
    const int tid  = threadIdx.x;
    const int lane = tid & 63;
    const int w    = tid >> 6;             // 0..7
    const int wr   = w >> 1, wc = w & 1;
    const int m0 = blockIdx.y * 128;
    const int n0 = blockIdx.x * 128;

    floatx4 acc[2][4];
#pragma unroll
    for (int i = 0; i < 2; ++i)
#pragma unroll
        for (int j = 0; j < 4; ++j) acc[i][j] = (floatx4){0.f, 0.f, 0.f, 0.f};

    // staging: lane l -> row w*16 + (l>>2), phys slot l&3 (linear LDS dest);
    // source column carries the inverse swizzle.
    const int srow = w * 16 + (lane >> 2);
    const int sq   = (lane & 3) ^ swz4(srow);

#define STAGE_IN(buf, k0)                                                      \
    {                                                                          \
        glds16(xb + (size_t)(m0 + srow) * 1024 + (k0) + sq * 8,                \
               &As[buf][(w * 16) * 32]);                                       \
        glds16(wT + (size_t)(n0 + srow) * 1024 + (k0) + sq * 8,                \
               &Bs[buf][(w * 16) * 32]);                                       \
    }

    STAGE_IN(0, 0)
    int cur = 0;
    for (int t = 0; t < 32; ++t) {
        if (t < 31) {
            STAGE_IN(cur ^ 1, (t + 1) * 32)
            asm volatile("s_waitcnt vmcnt(2)\ns_barrier" ::: "memory");
        } else {
            asm volatile("s_waitcnt vmcnt(0)\ns_barrier" ::: "memory");
        }
        short8v af[2], bf[4];
#pragma unroll
        for (int i = 0; i < 2; ++i) {
            const int ra = wr * 32 + i * 16 + (lane & 15);
            const int pa = (lane >> 4) ^ swz4(ra);
            af[i] = *(const short8v*)&As[cur][ra * 32 + pa * 8];
        }
#pragma unroll
        for (int j = 0; j < 4; ++j) {
            const int rb = wc * 64 + j * 16 + (lane & 15);
            const int pb = (lane >> 4) ^ swz4(rb);
            bf[j] = *(const short8v*)&Bs[cur][rb * 32 + pb * 8];
        }
        __builtin_amdgcn_s_setprio(1);
#pragma unroll
        for (int i = 0; i < 2; ++i)
#pragma unroll
            for (int j = 0; j < 4; ++j)
                acc[i][j] = __builtin_amdgcn_mfma_f32_16x16x32_bf16(
                    af[i], bf[j], acc[i][j], 0, 0, 0);
        __builtin_amdgcn_s_setprio(0);
        if (t < 31) asm volatile("s_barrier" ::: "memory");
        cur ^= 1;
    }

    const int seg = n0 >> 10;                 // block-uniform: 0 q,1 k,2 v,3 gate
    const int colbase = (n0 & 1023) + wc * 64 + (lane & 15);
#pragma unroll
    for (int i = 0; i < 2; ++i) {
        const int rowb = m0 + wr * 32 + i * 16 + (lane >> 4) * 4;
#pragma unroll
        for (int j = 0; j < 4; ++j) {
            const int col = colbase + j * 16;
#pragma unroll
            for (int r2 = 0; r2 < 4; ++r2) {
                float v = acc[i][j][r2];
                size_t o = (size_t)(rowb + r2) * 1024 + col;
                if (seg == 0)      qb[o] = f2bf(elu1(v));
                else if (seg == 1) kb[o] = f2bf(elu1(v));
                else if (seg == 2) vb[o] = f2bf(v);
                else               gtb[o] = f2bf(1.f / (1.f + expf(-v)));
            }
        }
    }
}

// ---------------------------------------------------------------------------
// Kernel C: output GEMM 64x128, BK=64, 512 threads / 8 waves (2m x 4n, wave
// tile 32x32, acc[2][2]), dbuf 48KB, counted vmcnt(3) + raw barriers.
// ---------------------------------------------------------------------------
__global__ __launch_bounds__(512) void gemm_out_mfma(
    const unsigned short* __restrict__ ab, const unsigned short* __restrict__ wT,
    float* __restrict__ out) {
    __shared__ short As[2][64 * 64];       // 16 KB
    __shared__ short Bs[2][128 * 64];      // 32 KB
    const int tid  = threadIdx.x;
    const int lane = tid & 63;
    const int w    = tid >> 6;             // 0..7
    const int wm   = w >> 2, wn = w & 3;
    const int m0 = blockIdx.y * 64;        // grid (8,32)
    const int n0 = blockIdx.x * 128;

    floatx4 acc[2][2];
#pragma unroll
    for (int i = 0; i < 2; ++i)
#pragma unroll
        for (int j = 0; j < 2; ++j) acc[i][j] = (floatx4){0.f, 0.f, 0.f, 0.f};

    const int srow = (lane >> 3);
    const int schk = (lane & 7);

#define STAGE_OUT(buf, k0)                                                     \
    {                                                                          \
        const int rA = w * 8 + srow;                                           \
        const int cA = schk ^ (rA & 7);                                        \
        glds16(ab + (size_t)(m0 + rA) * 1024 + (k0) + cA * 8,                  \
               &As[buf][(w * 8) * 64]);                                        \
        _Pragma("unroll") for (int g = 0; g < 2; ++g) {                        \
            const int rB = g * 64 + w * 8 + srow;                              \
            const int cB = schk ^ (rB & 7);                                    \
            glds16(wT + (size_t)(n0 + rB) * 1024 + (k0) + cB * 8,              \
                   &Bs[buf][(g * 64 + w * 8) * 64]);                           \
        }                                                                      \
    }

    STAGE_OUT(0, 0)
    int cur = 0;
    for (int t = 0; t < 16; ++t) {
        if (t < 15) {
            STAGE_OUT(cur ^ 1, (t + 1) * 64)
            asm volatile("s_waitcnt vmcnt(3)\ns_barrier" ::: "memory");
        } else {
            asm volatile("s_waitcnt vmcnt(0)\ns_barrier" ::: "memory");
        }
        short8v af[2][2], bf[2][2];
#pragma unroll
        for (int i = 0; i < 2; ++i) {
            const int ra = wm * 32 + i * 16 + (lane & 15);
#pragma unroll
            for (int kk = 0; kk < 2; ++kk) {
                const int ca = (kk * 4 + (lane >> 4)) ^ (ra & 7);
                af[i][kk] = *(const short8v*)&As[cur][ra * 64 + ca * 8];
            }
        }
#pragma unroll
        for (int j = 0; j < 2; ++j) {
            const int rb = wn * 32 + j * 16 + (lane & 15);
#pragma unroll
            for (int kk = 0; kk < 2; ++kk) {
                const int cb = (kk * 4 + (lane >> 4)) ^ (rb & 7);
                bf[j][kk] = *(const short8v*)&Bs[cur][rb * 64 + cb * 8];
            }
        }
        __builtin_amdgcn_s_setprio(1);
#pragma unroll
        for (int kk = 0; kk < 2; ++kk)
#pragma unroll
            for (int i = 0; i < 2; ++i)
#pragma unroll
                for (int j = 0; j < 2; ++j)
                    acc[i][j] = __builtin_amdgcn_mfma_f32_16x16x32_bf16(
                        af[i][kk], bf[j][kk], acc[i][j], 0, 0, 0);
        __builtin_amdgcn_s_setprio(0);
        if (t < 15) asm volatile("s_barrier" ::: "memory");
        cur ^= 1;
    }

    const int colbase = n0 + wn * 32 + (lane & 15);
#pragma unroll
    for (int i = 0; i < 2; ++i) {
        const int rowb = m0 + wm * 32 + i * 16 + (lane >> 4) * 4;
#pragma unroll
        for (int j = 0; j < 2; ++j) {
#pragma unroll
            for (int r2 = 0; r2 < 4; ++r2)
                out[(size_t)(rowb + r2) * 1024 + colbase + j * 16] = acc[i][j][r2];
        }
    }
}

// ---------------------------------------------------------------------------
// Kernel B1 (MFMA): St = (K^T V)^T stored bf16 [i][j]; ksum[j] = colsum(K).
// ---------------------------------------------------------------------------
__global__ __launch_bounds__(256) void chunk_state(
    const unsigned short* __restrict__ kb, const unsigned short* __restrict__ vb,
    unsigned short* __restrict__ St, float* __restrict__ ksum) {
    __shared__ unsigned short Kt[64 * 64];   // [d][t] swizzled
    __shared__ unsigned short Vt[64 * 64];   // [i][t] swizzled
    const int tid = threadIdx.x;
    const int lane = tid & 63;
    const int w = tid >> 6;
    const int c = blockIdx.x, h = blockIdx.y, b = blockIdx.z;
    const size_t gbase = ((size_t)(b * T_ + c * 64)) * 1024 + h * 64;
    const size_t cb = (size_t)((b * H_ + h) * NC_ + c);

#pragma unroll
    for (int rep = 0; rep < 2; ++rep) {
        int idx = tid + rep * 256;
        int s = idx >> 3, ig = (idx & 7) * 8;
        short8v kv = *(const short8v*)&kb[gbase + (size_t)s * 1024 + ig];
        short8v vv = *(const short8v*)&vb[gbase + (size_t)s * 1024 + ig];
#pragma unroll
        for (int e = 0; e < 8; ++e) {
            *(unsigned short*)((char*)Kt + swzb(ig + e, s * 2)) = (unsigned short)kv[e];
            *(unsigned short*)((char*)Vt + swzb(ig + e, s * 2)) = (unsigned short)vv[e];
        }
    }
    __syncthreads();

    if (tid < 64) {
        float ssum = 0.f;
#pragma unroll
        for (int tb = 0; tb < 8; ++tb) {
            short8v kk = *(const short8v*)((char*)Kt + swzb(tid, tb * 16));
#pragma unroll
            for (int e = 0; e < 8; ++e) ssum += bf2f((unsigned short)kk[e]);
        }
        ksum[cb * 64 + tid] = ssum;
    }

    const int ir  = w * 16 + (lane & 15);
    const int klo = ((lane >> 4) * 8) * 2;
    short8v a0 = *(const short8v*)((char*)Vt + swzb(ir, klo));
    short8v a1 = *(const short8v*)((char*)Vt + swzb(ir, 64 + klo));
#pragma unroll
    for (int jt = 0; jt < 4; ++jt) {
        const int jr = jt * 16 + (lane & 15);
        short8v b0 = *(const short8v*)((char*)Kt + swzb(jr, klo));
        short8v b1 = *(const short8v*)((char*)Kt + swzb(jr, 64 + klo));
        floatx4 a = (floatx4){0.f, 0.f, 0.f, 0.f};
        a = __builtin_amdgcn_mfma_f32_16x16x32_bf16(a0, b0, a, 0, 0, 0);
        a = __builtin_amdgcn_mfma_f32_16x16x32_bf16(a1, b1, a, 0, 0, 0);
#pragma unroll
        for (int r = 0; r < 4; ++r) {
            int irow = w * 16 + (lane >> 4) * 4 + r;
            St[cb * 4096 + (size_t)irow * 64 + jr] = f2bf(a[r]);
        }
    }
}

// ---------------------------------------------------------------------------
// Kernel B3 (MFMA): prefix-fold + scores=QK^T -> mask -> bf16 strip ->
// num=strip*[V|1] + Q*[P|kpre].  den folded via column 64.
// ---------------------------------------------------------------------------
__global__ __launch_bounds__(256) void attn_out(
    const unsigned short* __restrict__ qb, const unsigned short* __restrict__ kb,
    const unsigned short* __restrict__ vb, const unsigned short* __restrict__ St,
    const float* __restrict__ ksum, const unsigned short* __restrict__ gtb,
    unsigned short* __restrict__ att_b) {
    __shared__ unsigned short Qs[64 * 64];    // [t][d]
    __shared__ unsigned short Ks[64 * 64];    // [s][d]
    __shared__ unsigned short Vts[80 * 64];   // [i][s], row64=ones
    __shared__ unsigned short Pts[80 * 64];   // [i][j], row64=kpre
    __shared__ unsigned short Sp[4 * 16 * 64];
    const int tid = threadIdx.x;
    const int lane = tid & 63;
    const int w = tid >> 6;
    const int c = blockIdx.x, h = blockIdx.y, b = blockIdx.z;
    const size_t gbase = ((size_t)(b * T_ + c * 64)) * 1024 + h * 64;
    const size_t cb0 = (size_t)(b * H_ + h) * NC_;

#pragma unroll
    for (int rep = 0; rep < 2; ++rep) {
        int idx = tid + rep * 256;
        int r = idx >> 3, ig = (idx & 7) * 8;
        short8v qv = *(const short8v*)&qb[gbase + (size_t)r * 1024 + ig];
        short8v kv = *(const short8v*)&kb[gbase + (size_t)r * 1024 + ig];
        *(short8v*)((char*)Qs + swzb(r, ig * 2)) = qv;
        *(short8v*)((char*)Ks + swzb(r, ig * 2)) = kv;
    }
#pragma unroll
    for (int rep = 0; rep < 2; ++rep) {
        int idx = tid + rep * 256;
        int s = idx >> 3, ig = (idx & 7) * 8;
        short8v vv = *(const short8v*)&vb[gbase + (size_t)s * 1024 + ig];
#pragma unroll
        for (int e = 0; e < 8; ++e)
            *(unsigned short*)((char*)Vts + swzb(ig + e, s * 2)) = (unsigned short)vv[e];
    }
    // prefix-fold P^T = sum_{c'<c} St_{c'}  (bf16 terms, f32 accumulate)
    {
        const int prow = tid >> 2;
        const int pj0  = (tid & 3) * 16;
        float pacc[16];
#pragma unroll
        for (int e = 0; e < 16; ++e) pacc[e] = 0.f;
        for (int cc = 0; cc < c; ++cc) {
            const unsigned short* sp = St + (cb0 + cc) * 4096 + (size_t)prow * 64 + pj0;
            short8v s0 = *(const short8v*)sp;
            short8v s1 = *(const short8v*)(sp + 8);
#pragma unroll
            for (int e = 0; e < 8; ++e) {
                pacc[e]     += bf2f((unsigned short)s0[e]);
                pacc[8 + e] += bf2f((unsigned short)s1[e]);
            }
        }
        unsigned short o[16];
#pragma unroll
        for (int e = 0; e < 16; ++e) o[e] = f2bf(pacc[e]);
        *(short8v*)((char*)Pts + swzb(prow, pj0 * 2))      = *(short8v*)&o[0];
        *(short8v*)((char*)Pts + swzb(prow, pj0 * 2 + 16)) = *(short8v*)&o[8];
    }
    if (tid < 64) {
        float kp = 0.f;
        for (int cc = 0; cc < c; ++cc) kp += ksum[(cb0 + cc) * 64 + tid];
        *(unsigned short*)((char*)Vts + swzb(64, tid * 2)) = 0x3F80;
        *(unsigned short*)((char*)Pts + swzb(64, tid * 2)) = f2bf(kp);
    }
    if (tid < 240) {
        int rr = 65 + (tid >> 4), cc2 = (tid & 15) * 4;
#pragma unroll
        for (int e = 0; e < 4; ++e) {
            *(unsigned short*)((char*)Vts + swzb(rr, (cc2 + e) * 2)) = 0;
            *(unsigned short*)((char*)Pts + swzb(rr, (cc2 + e) * 2)) = 0;
        }
    }
    __syncthreads();

    const int t0  = w * 16;
    const int klo = ((lane >> 4) * 8) * 2;
    short8v qa0 = *(const short8v*)((char*)Qs + swzb(t0 + (lane & 15), klo));
    short8v qa1 = *(const short8v*)((char*)Qs + swzb(t0 + (lane & 15), 64 + klo));
    const int tl0 = t0 + (lane >> 4) * 4;

#pragma unroll
    for (int jt = 0; jt < 4; ++jt) {
        const int sr = jt * 16 + (lane & 15);
        short8v k0 = *(const short8v*)((char*)Ks + swzb(sr, klo));
        short8v k1 = *(const short8v*)((char*)Ks + swzb(sr, 64 + klo));
        floatx4 sc = (floatx4){0.f, 0.f, 0.f, 0.f};
        __builtin_amdgcn_s_setprio(1);
        sc = __builtin_amdgcn_mfma_f32_16x16x32_bf16(qa0, k0, sc, 0, 0, 0);
        sc = __builtin_amdgcn_mfma_f32_16x16x32_bf16(qa1, k1, sc, 0, 0, 0);
        __builtin_amdgcn_s_setprio(0);
#pragma unroll
        for (int r = 0; r < 4; ++r) {
            float val = (sr <= tl0 + r) ? sc[r] : 0.f;
            *(unsigned short*)((char*)Sp + w * 2048 +
                swzb((lane >> 4) * 4 + r, sr * 2)) = f2bf(val);
        }
    }

    short8v sa0 = *(const short8v*)((char*)Sp + w * 2048 + swzb(lane & 15, klo));
    short8v sa1 = *(const short8v*)((char*)Sp + w * 2048 + swzb(lane & 15, 64 + klo));
    floatx4 cn[5];
#pragma unroll
    for (int it = 0; it < 5; ++it) {
        const int ir = it * 16 + (lane & 15);
        short8v bv0 = *(const short8v*)((char*)Vts + swzb(ir, klo));
        short8v bv1 = *(const short8v*)((char*)Vts + swzb(ir, 64 + klo));
        short8v bp0 = *(const short8v*)((char*)Pts + swzb(ir, klo));
        short8v bp1 = *(const short8v*)((char*)Pts + swzb(ir, 64 + klo));
        floatx4 a = (floatx4){0.f, 0.f, 0.f, 0.f};
        __builtin_amdgcn_s_setprio(1);
        a = __builtin_amdgcn_mfma_f32_16x16x32_bf16(sa0, bv0, a, 0, 0, 0);
        a = __builtin_amdgcn_mfma_f32_16x16x32_bf16(sa1, bv1, a, 0, 0, 0);
        a = __builtin_amdgcn_mfma_f32_16x16x32_bf16(qa0, bp0, a, 0, 0, 0);
        a = __builtin_amdgcn_mfma_f32_16x16x32_bf16(qa1, bp1, a, 0, 0, 0);
        __builtin_amdgcn_s_setprio(0);
        cn[it] = a;
    }

#pragma unroll
    for (int r = 0; r < 4; ++r) {
        float den = __shfl(cn[4][r], lane & 48);
        float inv = 1.f / (den + 1e-6f);
        const size_t rowg = gbase + (size_t)(t0 + (lane >> 4) * 4 + r) * 1024;
#pragma unroll
        for (int it = 0; it < 4; ++it) {
            int i = it * 16 + (lane & 15);
            float g = bf2f(gtb[rowg + i]);
            att_b[rowg + i] = f2bf(cn[it][r] * inv * g);
        }
    }
}

extern "C" void kernel_launch(void* const* d_in, const int* in_sizes, int n_in,
                              void* d_out, int out_size, void* d_ws, size_t ws_size,
                              hipStream_t stream) {
    const float* x     = (const float*)d_in[0];
    const float* wqkv  = (const float*)d_in[1];
    const float* wgate = (const float*)d_in[2];
    const float* wout  = (const float*)d_in[3];
    float* out = (float*)d_out;

    char* ws = (char*)d_ws;
    unsigned short* xb    = (unsigned short*)(ws + 0);            // 4 MB
    unsigned short* wT    = (unsigned short*)(ws + (4u  << 20));  // 8 MB
    unsigned short* woutT = (unsigned short*)(ws + (12u << 20));  // 2 MB
    unsigned short* qb    = (unsigned short*)(ws + (14u << 20));  // 4 MB
    unsigned short* kb    = (unsigned short*)(ws + (18u << 20));  // 4 MB
    unsigned short* vb    = (unsigned short*)(ws + (22u << 20));  // 4 MB
    unsigned short* gtb   = (unsigned short*)(ws + (26u << 20));  // 4 MB
    unsigned short* St    = (unsigned short*)(ws + (30u << 20));  // 4 MB
    float*          ksum  = (float*)(ws + (34u << 20));           // 128 KB
    unsigned short* att_b = (unsigned short*)(ws + (35u << 20));  // 4 MB

    prep<<<6144, 256, 0, stream>>>(x, wqkv, wgate, wout, xb, wT, woutT);

    dim3 g1(NTOT_ / 128, M_ / 128);         // (32,16)
    gemm_in_mfma<<<g1, 512, 0, stream>>>(xb, wT, qb, kb, vb, gtb);

    dim3 gs(NC_, H_, B_);                   // (16,16,2)
    chunk_state<<<gs, 256, 0, stream>>>(kb, vb, St, ksum);

    attn_out<<<gs, 256, 0, stream>>>(qb, kb, vb, St, ksum, gtb, att_b);

    dim3 g3(DIM_ / 128, M_ / 64);           // (8,32)
    gemm_out_mfma<<<g3, 512, 0, stream>>>(att_b, woutT, out);
}

// Round 15
// 69.163 us; speedup vs baseline: 1.0821x; 1.0821x over previous
//
#include <hip/hip_runtime.h>
#include <hip/hip_bf16.h>
#include <math.h>

#define B_    2
#define T_    1024
#define DIM_  1024
#define H_    16
#define D_    64
#define M_    (B_ * T_)      // 2048 rows
#define NQKV_ 3072
#define NTOT_ 4096
#define NC_   16             // chunks of 64 along T

typedef __attribute__((ext_vector_type(8))) short short8v;   // 8 bf16
typedef __attribute__((ext_vector_type(4))) float floatx4;

__device__ __forceinline__ float elu1(float x) {
    return x > 0.f ? x + 1.f : expf(x);
}
__device__ __forceinline__ unsigned short f2bf(float f) {
    unsigned int u = __float_as_uint(f);
    return (unsigned short)((u + 0x7FFFu + ((u >> 16) & 1u)) >> 16);   // RNE
}
__device__ __forceinline__ float bf2f(unsigned short s) {
    return __uint_as_float((unsigned int)s << 16);
}
// XOR-swizzled byte offset within a [rows][64]bf16 LDS tile (128B rows)
__device__ __forceinline__ int swzb(int row, int byte) {
    return row * 128 + (byte ^ ((row & 7) << 4));
}
__device__ __forceinline__ void glds16(const unsigned short* g, short* l) {
    __builtin_amdgcn_global_load_lds(
        (const __attribute__((address_space(1))) unsigned int*)g,
        (__attribute__((address_space(3))) unsigned int*)l, 16, 0, 0);
}

// ---------------------------------------------------------------------------
// prep: fused cast_x + 3x weight transpose+cast.  Flat grid, role by blockIdx.
// ---------------------------------------------------------------------------
__device__ __forceinline__ void transw_body(
    const float* __restrict__ src, unsigned short* __restrict__ dst, int srcN,
    int n0, int k0, float (*t)[33], int tid) {
    const int r  = tid >> 3;
    const int c4 = (tid & 7) * 4;
    float4 v = *(const float4*)&src[(size_t)(k0 + r) * srcN + n0 + c4];
    t[c4 + 0][r] = v.x; t[c4 + 1][r] = v.y; t[c4 + 2][r] = v.z; t[c4 + 3][r] = v.w;
    __syncthreads();
    unsigned short o[4];
    o[0] = f2bf(t[tid >> 3][(tid & 7) * 4 + 0]);
    o[1] = f2bf(t[tid >> 3][(tid & 7) * 4 + 1]);
    o[2] = f2bf(t[tid >> 3][(tid & 7) * 4 + 2]);
    o[3] = f2bf(t[tid >> 3][(tid & 7) * 4 + 3]);
    *(unsigned long long*)&dst[(size_t)(n0 + (tid >> 3)) * 1024 + k0 + (tid & 7) * 4] =
        *(unsigned long long*)o;
}

__global__ __launch_bounds__(256) void prep(
    const float* __restrict__ x, const float* __restrict__ wqkv,
    const float* __restrict__ wgate, const float* __restrict__ wout,
    unsigned short* __restrict__ xb, unsigned short* __restrict__ wT,
    unsigned short* __restrict__ woutT) {
    __shared__ float t[32][33];
    const int blk = blockIdx.x;
    const int tid = threadIdx.x;
    if (blk < 1024) {
        int i = blk * 256 + tid;
        float4 v0 = ((const float4*)x)[i * 2];
        float4 v1 = ((const float4*)x)[i * 2 + 1];
        short8v o;
        o[0]=f2bf(v0.x); o[1]=f2bf(v0.y); o[2]=f2bf(v0.z); o[3]=f2bf(v0.w);
        o[4]=f2bf(v1.x); o[5]=f2bf(v1.y); o[6]=f2bf(v1.z); o[7]=f2bf(v1.w);
        *(short8v*)&xb[(size_t)i * 8] = o;
    } else if (blk < 4096) {
        int l = blk - 1024;
        transw_body(wqkv, wT, 3072, (l % 96) * 32, (l / 96) * 32, t, tid);
    } else if (blk < 5120) {
        int l = blk - 4096;
        transw_body(wgate, wT + (size_t)3072 * 1024, 1024, (l % 32) * 32, (l / 32) * 32, t, tid);
    } else {
        int l = blk - 5120;
        transw_body(wout, woutT, 1024, (l % 32) * 32, (l / 32) * 32, t, tid);
    }
}

// ---------------------------------------------------------------------------
// Kernel A: input GEMM 128x128, BK=64, 512 threads (8 waves, 16 waves/CU),
// dbuf LDS 64KB (2 blocks/CU), counted vmcnt(4) + raw barriers, setprio.
// Wave w owns rows [wr*32,+32) x cols [wc*64,+64), wr=w>>1, wc=w&1.
// (Round-13 config: BK=64 > BK=32 (r14) and > 96KB/1-block (r12).)
// ---------------------------------------------------------------------------
__global__ __launch_bounds__(512) void gemm_in_mfma(
    const unsigned short* __restrict__ xb, const unsigned short* __restrict__ wT,
    unsigned short* __restrict__ qb, unsigned short* __restrict__ kb,
    unsigned short* __restrict__ vb, unsigned short* __restrict__ gtb) {
    __shared__ short As[2][128 * 64];      // 32 KB
    __shared__ short Bs[2][128 * 64];      // 32 KB
    const int tid  = threadIdx.x;
    const int lane = tid & 63;
    const int w    = tid >> 6;             // 0..7
    const int wr   = w >> 1, wc = w & 1;
    const int m0 = blockIdx.y * 128;
    const int n0 = blockIdx.x * 128;

    floatx4 acc[2][4];
#pragma unroll
    for (int i = 0; i < 2; ++i)
#pragma unroll
        for (int j = 0; j < 4; ++j) acc[i][j] = (floatx4){0.f, 0.f, 0.f, 0.f};

    const int srow = (lane >> 3);          // 0..7 within 8-row group
    const int schk = (lane & 7);           // 16B chunk within row

#define STAGE_IN(buf, k0)                                                      \
    _Pragma("unroll") for (int g = 0; g < 2; ++g) {                            \
        const int r = w * 16 + g * 8 + srow;                                   \
        const int c = schk ^ (r & 7);                                          \
        glds16(xb + (size_t)(m0 + r) * 1024 + (k0) + c * 8,                    \
               &As[buf][(w * 16 + g * 8) * 64]);                               \
        glds16(wT + (size_t)(n0 + r) * 1024 + (k0) + c * 8,                    \
               &Bs[buf][(w * 16 + g * 8) * 64]);                               \
    }

    STAGE_IN(0, 0)
    int cur = 0;
    for (int t = 0; t < 16; ++t) {
        if (t < 15) {
            STAGE_IN(cur ^ 1, (t + 1) * 64)
            asm volatile("s_waitcnt vmcnt(4)\ns_barrier" ::: "memory");
        } else {
            asm volatile("s_waitcnt vmcnt(0)\ns_barrier" ::: "memory");
        }
        short8v af[2][2], bf[4][2];
#pragma unroll
        for (int i = 0; i < 2; ++i) {
            const int ra = wr * 32 + i * 16 + (lane & 15);
#pragma unroll
            for (int kk = 0; kk < 2; ++kk) {
                const int ca = (kk * 4 + (lane >> 4)) ^ (ra & 7);
                af[i][kk] = *(const short8v*)&As[cur][ra * 64 + ca * 8];
            }
        }
#pragma unroll
        for (int j = 0; j < 4; ++j) {
            const int rb = wc * 64 + j * 16 + (lane & 15);
#pragma unroll
            for (int kk = 0; kk < 2; ++kk) {
                const int cb = (kk * 4 + (lane >> 4)) ^ (rb & 7);
                bf[j][kk] = *(const short8v*)&Bs[cur][rb * 64 + cb * 8];
            }
        }
        __builtin_amdgcn_s_setprio(1);
#pragma unroll
        for (int kk = 0; kk < 2; ++kk)
#pragma unroll
            for (int i = 0; i < 2; ++i)
#pragma unroll
                for (int j = 0; j < 4; ++j)
                    acc[i][j] = __builtin_amdgcn_mfma_f32_16x16x32_bf16(
                        af[i][kk], bf[j][kk], acc[i][j], 0, 0, 0);
        __builtin_amdgcn_s_setprio(0);
        if (t < 15) asm volatile("s_barrier" ::: "memory");
        cur ^= 1;
    }

    const int seg = n0 >> 10;                 // block-uniform: 0 q,1 k,2 v,3 gate
    const int colbase = (n0 & 1023) + wc * 64 + (lane & 15);
#pragma unroll
    for (int i = 0; i < 2; ++i) {
        const int rowb = m0 + wr * 32 + i * 16 + (lane >> 4) * 4;
#pragma unroll
        for (int j = 0; j < 4; ++j) {
            const int col = colbase + j * 16;
#pragma unroll
            for (int r2 = 0; r2 < 4; ++r2) {
                float v = acc[i][j][r2];
                size_t o = (size_t)(rowb + r2) * 1024 + col;
                if (seg == 0)      qb[o] = f2bf(elu1(v));
                else if (seg == 1) kb[o] = f2bf(elu1(v));
                else if (seg == 2) vb[o] = f2bf(v);
                else               gtb[o] = f2bf(1.f / (1.f + expf(-v)));
            }
        }
    }
}

// ---------------------------------------------------------------------------
// Kernel C: output GEMM 64x64 tile, 256 threads / 4 waves (2m x 2n, wave tile
// 32x32, acc[2][2]), BK=64, dbuf 32KB, grid (16,32)=512 blocks -> 2 blocks/CU.
// counted vmcnt(4) + raw barriers, setprio.
// ---------------------------------------------------------------------------
__global__ __launch_bounds__(256) void gemm_out_mfma(
    const unsigned short* __restrict__ ab, const unsigned short* __restrict__ wT,
    float* __restrict__ out) {
    __shared__ short As[2][64 * 64];       // 8 KB each buf
    __shared__ short Bs[2][64 * 64];
    const int tid  = threadIdx.x;
    const int lane = tid & 63;
    const int w    = tid >> 6;             // 0..3
    const int wm   = w >> 1, wn = w & 1;
    const int m0 = blockIdx.y * 64;        // grid (16,32)
    const int n0 = blockIdx.x * 64;

    floatx4 acc[2][2];
#pragma unroll
    for (int i = 0; i < 2; ++i)
#pragma unroll
        for (int j = 0; j < 2; ++j) acc[i][j] = (floatx4){0.f, 0.f, 0.f, 0.f};

    const int srow = (lane >> 3);          // 0..7
    const int schk = (lane & 7);

#define STAGE_OUT(buf, k0)                                                     \
    _Pragma("unroll") for (int g = 0; g < 2; ++g) {                            \
        const int r = g * 32 + w * 8 + srow;                                   \
        const int c = schk ^ (r & 7);                                          \
        glds16(ab + (size_t)(m0 + r) * 1024 + (k0) + c * 8,                    \
               &As[buf][(g * 32 + w * 8) * 64]);                               \
        glds16(wT + (size_t)(n0 + r) * 1024 + (k0) + c * 8,                    \
               &Bs[buf][(g * 32 + w * 8) * 64]);                               \
    }

    STAGE_OUT(0, 0)
    int cur = 0;
    for (int t = 0; t < 16; ++t) {
        if (t < 15) {
            STAGE_OUT(cur ^ 1, (t + 1) * 64)
            asm volatile("s_waitcnt vmcnt(4)\ns_barrier" ::: "memory");
        } else {
            asm volatile("s_waitcnt vmcnt(0)\ns_barrier" ::: "memory");
        }
        short8v af[2][2], bf[2][2];
#pragma unroll
        for (int i = 0; i < 2; ++i) {
            const int ra = wm * 32 + i * 16 + (lane & 15);
#pragma unroll
            for (int kk = 0; kk < 2; ++kk) {
                const int ca = (kk * 4 + (lane >> 4)) ^ (ra & 7);
                af[i][kk] = *(const short8v*)&As[cur][ra * 64 + ca * 8];
            }
        }
#pragma unroll
        for (int j = 0; j < 2; ++j) {
            const int rb = wn * 32 + j * 16 + (lane & 15);
#pragma unroll
            for (int kk = 0; kk < 2; ++kk) {
                const int cb = (kk * 4 + (lane >> 4)) ^ (rb & 7);
                bf[j][kk] = *(const short8v*)&Bs[cur][rb * 64 + cb * 8];
            }
        }
        __builtin_amdgcn_s_setprio(1);
#pragma unroll
        for (int kk = 0; kk < 2; ++kk)
#pragma unroll
            for (int i = 0; i < 2; ++i)
#pragma unroll
                for (int j = 0; j < 2; ++j)
                    acc[i][j] = __builtin_amdgcn_mfma_f32_16x16x32_bf16(
                        af[i][kk], bf[j][kk], acc[i][j], 0, 0, 0);
        __builtin_amdgcn_s_setprio(0);
        if (t < 15) asm volatile("s_barrier" ::: "memory");
        cur ^= 1;
    }

    const int colbase = n0 + wn * 32 + (lane & 15);
#pragma unroll
    for (int i = 0; i < 2; ++i) {
        const int rowb = m0 + wm * 32 + i * 16 + (lane >> 4) * 4;
#pragma unroll
        for (int j = 0; j < 2; ++j) {
#pragma unroll
            for (int r2 = 0; r2 < 4; ++r2)
                out[(size_t)(rowb + r2) * 1024 + colbase + j * 16] = acc[i][j][r2];
        }
    }
}

// ---------------------------------------------------------------------------
// Kernel B1 (MFMA): St = (K^T V)^T stored bf16 [i][j]; ksum[j] = colsum(K).
// ---------------------------------------------------------------------------
__global__ __launch_bounds__(256) void chunk_state(
    const unsigned short* __restrict__ kb, const unsigned short* __restrict__ vb,
    unsigned short* __restrict__ St, float* __restrict__ ksum) {
    __shared__ unsigned short Kt[64 * 64];   // [d][t] swizzled
    __shared__ unsigned short Vt[64 * 64];   // [i][t] swizzled
    const int tid = threadIdx.x;
    const int lane = tid & 63;
    const int w = tid >> 6;
    const int c = blockIdx.x, h = blockIdx.y, b = blockIdx.z;
    const size_t gbase = ((size_t)(b * T_ + c * 64)) * 1024 + h * 64;
    const size_t cb = (size_t)((b * H_ + h) * NC_ + c);

#pragma unroll
    for (int rep = 0; rep < 2; ++rep) {
        int idx = tid + rep * 256;
        int s = idx >> 3, ig = (idx & 7) * 8;
        short8v kv = *(const short8v*)&kb[gbase + (size_t)s * 1024 + ig];
        short8v vv = *(const short8v*)&vb[gbase + (size_t)s * 1024 + ig];
#pragma unroll
        for (int e = 0; e < 8; ++e) {
            *(unsigned short*)((char*)Kt + swzb(ig + e, s * 2)) = (unsigned short)kv[e];
            *(unsigned short*)((char*)Vt + swzb(ig + e, s * 2)) = (unsigned short)vv[e];
        }
    }
    __syncthreads();

    if (tid < 64) {
        float ssum = 0.f;
#pragma unroll
        for (int tb = 0; tb < 8; ++tb) {
            short8v kk = *(const short8v*)((char*)Kt + swzb(tid, tb * 16));
#pragma unroll
            for (int e = 0; e < 8; ++e) ssum += bf2f((unsigned short)kk[e]);
        }
        ksum[cb * 64 + tid] = ssum;
    }

    const int ir  = w * 16 + (lane & 15);
    const int klo = ((lane >> 4) * 8) * 2;
    short8v a0 = *(const short8v*)((char*)Vt + swzb(ir, klo));
    short8v a1 = *(const short8v*)((char*)Vt + swzb(ir, 64 + klo));
#pragma unroll
    for (int jt = 0; jt < 4; ++jt) {
        const int jr = jt * 16 + (lane & 15);
        short8v b0 = *(const short8v*)((char*)Kt + swzb(jr, klo));
        short8v b1 = *(const short8v*)((char*)Kt + swzb(jr, 64 + klo));
        floatx4 a = (floatx4){0.f, 0.f, 0.f, 0.f};
        a = __builtin_amdgcn_mfma_f32_16x16x32_bf16(a0, b0, a, 0, 0, 0);
        a = __builtin_amdgcn_mfma_f32_16x16x32_bf16(a1, b1, a, 0, 0, 0);
#pragma unroll
        for (int r = 0; r < 4; ++r) {
            int irow = w * 16 + (lane >> 4) * 4 + r;
            St[cb * 4096 + (size_t)irow * 64 + jr] = f2bf(a[r]);
        }
    }
}

// ---------------------------------------------------------------------------
// Kernel B3 (MFMA): prefix-fold + scores=QK^T -> mask -> bf16 strip ->
// num=strip*[V|1] + Q*[P|kpre].  den folded via column 64.
// ---------------------------------------------------------------------------
__global__ __launch_bounds__(256) void attn_out(
    const unsigned short* __restrict__ qb, const unsigned short* __restrict__ kb,
    const unsigned short* __restrict__ vb, const unsigned short* __restrict__ St,
    const float* __restrict__ ksum, const unsigned short* __restrict__ gtb,
    unsigned short* __restrict__ att_b) {
    __shared__ unsigned short Qs[64 * 64];    // [t][d]
    __shared__ unsigned short Ks[64 * 64];    // [s][d]
    __shared__ unsigned short Vts[80 * 64];   // [i][s], row64=ones
    __shared__ unsigned short Pts[80 * 64];   // [i][j], row64=kpre
    __shared__ unsigned short Sp[4 * 16 * 64];
    const int tid = threadIdx.x;
    const int lane = tid & 63;
    const int w = tid >> 6;
    const int c = blockIdx.x, h = blockIdx.y, b = blockIdx.z;
    const size_t gbase = ((size_t)(b * T_ + c * 64)) * 1024 + h * 64;
    const size_t cb0 = (size_t)(b * H_ + h) * NC_;

#pragma unroll
    for (int rep = 0; rep < 2; ++rep) {
        int idx = tid + rep * 256;
        int r = idx >> 3, ig = (idx & 7) * 8;
        short8v qv = *(const short8v*)&qb[gbase + (size_t)r * 1024 + ig];
        short8v kv = *(const short8v*)&kb[gbase + (size_t)r * 1024 + ig];
        *(short8v*)((char*)Qs + swzb(r, ig * 2)) = qv;
        *(short8v*)((char*)Ks + swzb(r, ig * 2)) = kv;
    }
#pragma unroll
    for (int rep = 0; rep < 2; ++rep) {
        int idx = tid + rep * 256;
        int s = idx >> 3, ig = (idx & 7) * 8;
        short8v vv = *(const short8v*)&vb[gbase + (size_t)s * 1024 + ig];
#pragma unroll
        for (int e = 0; e < 8; ++e)
            *(unsigned short*)((char*)Vts + swzb(ig + e, s * 2)) = (unsigned short)vv[e];
    }
    // prefix-fold P^T = sum_{c'<c} St_{c'}  (bf16 terms, f32 accumulate)
    {
        const int prow = tid >> 2;
        const int pj0  = (tid & 3) * 16;
        float pacc[16];
#pragma unroll
        for (int e = 0; e < 16; ++e) pacc[e] = 0.f;
        for (int cc = 0; cc < c; ++cc) {
            const unsigned short* sp = St + (cb0 + cc) * 4096 + (size_t)prow * 64 + pj0;
            short8v s0 = *(const short8v*)sp;
            short8v s1 = *(const short8v*)(sp + 8);
#pragma unroll
            for (int e = 0; e < 8; ++e) {
                pacc[e]     += bf2f((unsigned short)s0[e]);
                pacc[8 + e] += bf2f((unsigned short)s1[e]);
            }
        }
        unsigned short o[16];
#pragma unroll
        for (int e = 0; e < 16; ++e) o[e] = f2bf(pacc[e]);
        *(short8v*)((char*)Pts + swzb(prow, pj0 * 2))      = *(short8v*)&o[0];
        *(short8v*)((char*)Pts + swzb(prow, pj0 * 2 + 16)) = *(short8v*)&o[8];
    }
    if (tid < 64) {
        float kp = 0.f;
        for (int cc = 0; cc < c; ++cc) kp += ksum[(cb0 + cc) * 64 + tid];
        *(unsigned short*)((char*)Vts + swzb(64, tid * 2)) = 0x3F80;
        *(unsigned short*)((char*)Pts + swzb(64, tid * 2)) = f2bf(kp);
    }
    if (tid < 240) {
        int rr = 65 + (tid >> 4), cc2 = (tid & 15) * 4;
#pragma unroll
        for (int e = 0; e < 4; ++e) {
            *(unsigned short*)((char*)Vts + swzb(rr, (cc2 + e) * 2)) = 0;
            *(unsigned short*)((char*)Pts + swzb(rr, (cc2 + e) * 2)) = 0;
        }
    }
    __syncthreads();

    const int t0  = w * 16;
    const int klo = ((lane >> 4) * 8) * 2;
    short8v qa0 = *(const short8v*)((char*)Qs + swzb(t0 + (lane & 15), klo));
    short8v qa1 = *(const short8v*)((char*)Qs + swzb(t0 + (lane & 15), 64 + klo));
    const int tl0 = t0 + (lane >> 4) * 4;

#pragma unroll
    for (int jt = 0; jt < 4; ++jt) {
        const int sr = jt * 16 + (lane & 15);
        short8v k0 = *(const short8v*)((char*)Ks + swzb(sr, klo));
        short8v k1 = *(const short8v*)((char*)Ks + swzb(sr, 64 + klo));
        floatx4 sc = (floatx4){0.f, 0.f, 0.f, 0.f};
        __builtin_amdgcn_s_setprio(1);
        sc = __builtin_amdgcn_mfma_f32_16x16x32_bf16(qa0, k0, sc, 0, 0, 0);
        sc = __builtin_amdgcn_mfma_f32_16x16x32_bf16(qa1, k1, sc, 0, 0, 0);
        __builtin_amdgcn_s_setprio(0);
#pragma unroll
        for (int r = 0; r < 4; ++r) {
            float val = (sr <= tl0 + r) ? sc[r] : 0.f;
            *(unsigned short*)((char*)Sp + w * 2048 +
                swzb((lane >> 4) * 4 + r, sr * 2)) = f2bf(val);
        }
    }

    short8v sa0 = *(const short8v*)((char*)Sp + w * 2048 + swzb(lane & 15, klo));
    short8v sa1 = *(const short8v*)((char*)Sp + w * 2048 + swzb(lane & 15, 64 + klo));
    floatx4 cn[5];
#pragma unroll
    for (int it = 0; it < 5; ++it) {
        const int ir = it * 16 + (lane & 15);
        short8v bv0 = *(const short8v*)((char*)Vts + swzb(ir, klo));
        short8v bv1 = *(const short8v*)((char*)Vts + swzb(ir, 64 + klo));
        short8v bp0 = *(const short8v*)((char*)Pts + swzb(ir, klo));
        short8v bp1 = *(const short8v*)((char*)Pts + swzb(ir, 64 + klo));
        floatx4 a = (floatx4){0.f, 0.f, 0.f, 0.f};
        __builtin_amdgcn_s_setprio(1);
        a = __builtin_amdgcn_mfma_f32_16x16x32_bf16(sa0, bv0, a, 0, 0, 0);
        a = __builtin_amdgcn_mfma_f32_16x16x32_bf16(sa1, bv1, a, 0, 0, 0);
        a = __builtin_amdgcn_mfma_f32_16x16x32_bf16(qa0, bp0, a, 0, 0, 0);
        a = __builtin_amdgcn_mfma_f32_16x16x32_bf16(qa1, bp1, a, 0, 0, 0);
        __builtin_amdgcn_s_setprio(0);
        cn[it] = a;
    }

#pragma unroll
    for (int r = 0; r < 4; ++r) {
        float den = __shfl(cn[4][r], lane & 48);
        float inv = 1.f / (den + 1e-6f);
        const size_t rowg = gbase + (size_t)(t0 + (lane >> 4) * 4 + r) * 1024;
#pragma unroll
        for (int it = 0; it < 4; ++it) {
            int i = it * 16 + (lane & 15);
            float g = bf2f(gtb[rowg + i]);
            att_b[rowg + i] = f2bf(cn[it][r] * inv * g);
        }
    }
}

extern "C" void kernel_launch(void* const* d_in, const int* in_sizes, int n_in,
                              void* d_out, int out_size, void* d_ws, size_t ws_size,
                              hipStream_t stream) {
    const float* x     = (const float*)d_in[0];
    const float* wqkv  = (const float*)d_in[1];
    const float* wgate = (const float*)d_in[2];
    const float* wout  = (const float*)d_in[3];
    float* out = (float*)d_out;

    char* ws = (char*)d_ws;
    unsigned short* xb    = (unsigned short*)(ws + 0);            // 4 MB
    unsigned short* wT    = (unsigned short*)(ws + (4u  << 20));  // 8 MB
    unsigned short* woutT = (unsigned short*)(ws + (12u << 20));  // 2 MB
    unsigned short* qb    = (unsigned short*)(ws + (14u << 20));  // 4 MB
    unsigned short* kb    = (unsigned short*)(ws + (18u << 20));  // 4 MB
    unsigned short* vb    = (unsigned short*)(ws + (22u << 20));  // 4 MB
    unsigned short* gtb   = (unsigned short*)(ws + (26u << 20));  // 4 MB
    unsigned short* St    = (unsigned short*)(ws + (30u << 20));  // 4 MB
    float*          ksum  = (float*)(ws + (34u << 20));           // 128 KB
    unsigned short* att_b = (unsigned short*)(ws + (35u << 20));  // 4 MB

    prep<<<6144, 256, 0, stream>>>(x, wqkv, wgate, wout, xb, wT, woutT);

    dim3 g1(NTOT_ / 128, M_ / 128);         // (32,16)
    gemm_in_mfma<<<g1, 512, 0, stream>>>(xb, wT, qb, kb, vb, gtb);

    dim3 gs(NC_, H_, B_);                   // (16,16,2)
    chunk_state<<<gs, 256, 0, stream>>>(kb, vb, St, ksum);

    attn_out<<<gs, 256, 0, stream>>>(qb, kb, vb, St, ksum, gtb, att_b);

    dim3 g3(DIM_ / 64, M_ / 64);            // (16,32) = 512 blocks
    gemm_out_mfma<<<g3, 256, 0, stream>>>(att_b, woutT, out);
}